// Round 4
// baseline (731.507 us; speedup 1.0000x reference)
//
#include <hip/hip_runtime.h>
#include <hip/hip_bf16.h>

// SimGCL / LightGCN 2-layer propagation — round 9.
//   r8 -> r9 (post-mortem: fused_scatter 92us @ VALUBusy 2.2%, WRITE 100MB
//   for a 16MB pairs array — 28B bucket runs destroyed write coalescing;
//   the whole bucket partition costs ~215us just to group edges by dest):
//   - Partition replaced by direct CSR build:
//       deg_kernel:    4M global atomicAdd into deg[] (600KB, L2-resident)
//       scan_block:    per-1024 block scan + dis=rsqrt(deg) + FUSED y=dis*x
//       scan_top/add:  hierarchical scan completion
//       scatter_kernel: pos=atomicAdd(&offsets[c],1); edata[pos]=row
//     Destructive-cursor trick: post-scatter offsets[c] == end[c], so agg
//     reads s=offsets[dest-1] (guard 0 at index -1), e=offsets[dest].
//     Deletes pairs (±32MB traffic), LDS hist, counting sort.
//   - agg unchanged from r8 (8-deep MLP, dual acc) for clean attribution.
//   Algebra (r4): y = dis*x (bf16); z[c] = dis[c]^2 * sum y[src];
//   out = (x + z/dis + dis * sum z[src]) / 3. No per-edge weights stored.

#define EMB_DIM 64
#define NPAD 150080  // padded node-region size (multiple of 64)

typedef float f32x4 __attribute__((ext_vector_type(4)));

__device__ __forceinline__ float bf_lo(unsigned int q) { return __uint_as_float(q << 16); }
__device__ __forceinline__ float bf_hi(unsigned int q) { return __uint_as_float(q & 0xffff0000u); }
__device__ __forceinline__ unsigned int f2bf(float f) {  // RNE
    unsigned int u = __float_as_uint(f);
    return (u + 0x7fffu + ((u >> 16) & 1u)) >> 16;
}

// (1) degree histogram: 4M global atomics into L2-resident deg[].
__global__ void deg_kernel(const int* __restrict__ cols,
                           int* __restrict__ deg, int E) {
    int tid = blockIdx.x * blockDim.x + threadIdx.x;
    int nthr = gridDim.x * blockDim.x;
    int E4 = E >> 2;
    const int4* c4 = (const int4*)cols;
    for (int i = tid; i < E4; i += nthr) {
        int4 c = c4[i];
        atomicAdd(&deg[c.x], 1);
        atomicAdd(&deg[c.y], 1);
        atomicAdd(&deg[c.z], 1);
        atomicAdd(&deg[c.w], 1);
    }
    for (int i = (E4 << 2) + tid; i < E; i += nthr)
        atomicAdd(&deg[cols[i]], 1);
}

// (2) per-1024-node block scan: degoff[n] := local exclusive scan;
//     bsum[blk] := block total; dis[n] = rsqrt(deg); fused y = dis*x (bf16).
__global__ void scan_block(int* __restrict__ degoff,
                           int* __restrict__ bsum,
                           float* __restrict__ dis,
                           const float* __restrict__ x,
                           unsigned short* __restrict__ yb, int N) {
    __shared__ int lds[1024];
    __shared__ float sdis[1024];
    int b = blockIdx.x, t = threadIdx.x;
    int nbase = b << 10;
    int n = nbase + t;
    int d = (n < N) ? degoff[n] : 0;
    lds[t] = d;
    sdis[t] = (d > 0) ? rsqrtf((float)d) : 0.0f;
    __syncthreads();
    for (int off = 1; off < 1024; off <<= 1) {
        int u = (t >= off) ? lds[t - off] : 0;
        __syncthreads();
        lds[t] += u;
        __syncthreads();
    }
    if (n < N) {
        degoff[n] = lds[t] - d;  // local exclusive
        dis[n] = sdis[t];
    }
    if (t == 1023) bsum[b] = lds[t];
    __syncthreads();

    // fused: y[row] = dis[row] * x[row] -> bf16
    int nmax = min(1024, N - nbase);
    for (int u = t; u < nmax * 16; u += 1024) {
        int lr = u >> 4;
        int part = u & 15;
        float dsc = sdis[lr];
        size_t o = (((size_t)(nbase + lr)) << 6) + part * 4;
        float4 vx = *(const float4*)(x + o);
        uint2 w;
        w.x = f2bf(vx.x * dsc) | (f2bf(vx.y * dsc) << 16);
        w.y = f2bf(vx.z * dsc) | (f2bf(vx.w * dsc) << 16);
        *(uint2*)(yb + o) = w;
    }
}

// (3) scan of block totals (nblk <= 1024), exclusive, in place.
__global__ void scan_top(int* __restrict__ bsum, int nblk) {
    __shared__ int lds[1024];
    int t = threadIdx.x;
    int v = (t < nblk) ? bsum[t] : 0;
    lds[t] = v;
    __syncthreads();
    for (int off = 1; off < 1024; off <<= 1) {
        int u = (t >= off) ? lds[t - off] : 0;
        __syncthreads();
        lds[t] += u;
        __syncthreads();
    }
    if (t < nblk) bsum[t] = lds[t] - v;
}

// (4) add block base -> global exclusive offsets.
__global__ void add_base(int* __restrict__ degoff,
                         const int* __restrict__ bsum, int N) {
    int n = blockIdx.x * blockDim.x + threadIdx.x;
    if (n < N) degoff[n] += bsum[n >> 10];
}

// (5) CSR scatter with destructive cursors: after this pass
//     degoff[c] == end[c] == start[c+1].
__global__ void scatter_kernel(const int* __restrict__ rows,
                               const int* __restrict__ cols,
                               int* __restrict__ degoff,
                               int* __restrict__ edata, int E) {
    int tid = blockIdx.x * blockDim.x + threadIdx.x;
    int nthr = gridDim.x * blockDim.x;
    int E4 = E >> 2;
    const int4* c4 = (const int4*)cols;
    const int4* r4 = (const int4*)rows;
    for (int i = tid; i < E4; i += nthr) {
        int4 c = c4[i];
        int4 r = r4[i];
        edata[atomicAdd(&degoff[c.x], 1)] = r.x;
        edata[atomicAdd(&degoff[c.y], 1)] = r.y;
        edata[atomicAdd(&degoff[c.z], 1)] = r.z;
        edata[atomicAdd(&degoff[c.w], 1)] = r.w;
    }
    for (int i = (E4 << 2) + tid; i < E; i += nthr)
        edata[atomicAdd(&degoff[cols[i]], 1)] = rows[i];
}

__device__ __forceinline__ void acc8(float* acc, uint4 q) {
    acc[0] += bf_lo(q.x);
    acc[1] += bf_hi(q.x);
    acc[2] += bf_lo(q.y);
    acc[3] += bf_hi(q.y);
    acc[4] += bf_lo(q.z);
    acc[5] += bf_hi(q.z);
    acc[6] += bf_lo(q.w);
    acc[7] += bf_hi(q.w);
}

// Wave = 8 subgroups x 8 lanes; each SUB owns ONE destination node
// (8 dests per wave). Lane holds 8 fp32 dims. Hot loop = 8 edges in
// flight per sub (64 gathers outstanding per wave), dual accumulators.
// offsets points at post-scatter cursors: s = offsets[dest-1] (guard 0
// at index -1), e = offsets[dest].
// !FINAL (embb = yb):  zb[c] = bf16( dis[c]^2 * acc )
//  FINAL (embb = zb):  out = (x + zb/dis + dis*acc)/3
template <bool FINAL>
__global__ void agg_kernel(const unsigned short* __restrict__ embb,
                           const int* __restrict__ edata,
                           const int* __restrict__ offsets,
                           const float* __restrict__ dis,
                           const float* __restrict__ x,        // FINAL only
                           unsigned short* __restrict__ outb,  // !FINAL
                           float* __restrict__ outf,           // FINAL
                           int n) {
    int wave = (blockIdx.x * blockDim.x + threadIdx.x) >> 6;
    int lane = threadIdx.x & 63;
    int sub = lane >> 3;
    int dest = (wave << 3) + sub;
    if (dest >= n) return;
    int dimo = (lane & 7) * 8;

    int s = offsets[dest - 1];  // dest==0 hits the zero guard slot
    int e = offsets[dest];

    float a0[8] = {0, 0, 0, 0, 0, 0, 0, 0};
    float a1[8] = {0, 0, 0, 0, 0, 0, 0, 0};
    const unsigned short* eb = embb + dimo;

    int k = s;
    int kfull = s + ((e - s) & ~7);
    for (; k < kfull; k += 8) {
        int s0 = edata[k];
        int s1 = edata[k + 1];
        int s2 = edata[k + 2];
        int s3 = edata[k + 3];
        int s4 = edata[k + 4];
        int s5 = edata[k + 5];
        int s6 = edata[k + 6];
        int s7 = edata[k + 7];
        uint4 q0 = *(const uint4*)(eb + ((size_t)s0 << 6));
        uint4 q1 = *(const uint4*)(eb + ((size_t)s1 << 6));
        uint4 q2 = *(const uint4*)(eb + ((size_t)s2 << 6));
        uint4 q3 = *(const uint4*)(eb + ((size_t)s3 << 6));
        uint4 q4 = *(const uint4*)(eb + ((size_t)s4 << 6));
        uint4 q5 = *(const uint4*)(eb + ((size_t)s5 << 6));
        uint4 q6 = *(const uint4*)(eb + ((size_t)s6 << 6));
        uint4 q7 = *(const uint4*)(eb + ((size_t)s7 << 6));
        acc8(a0, q0);
        acc8(a1, q1);
        acc8(a0, q2);
        acc8(a1, q3);
        acc8(a0, q4);
        acc8(a1, q5);
        acc8(a0, q6);
        acc8(a1, q7);
    }
    if (k < e) {  // tail < 8
        int s0 = edata[k];
        int s1 = (k + 1 < e) ? edata[k + 1] : -1;
        int s2 = (k + 2 < e) ? edata[k + 2] : -1;
        int s3 = (k + 3 < e) ? edata[k + 3] : -1;
        int s4 = (k + 4 < e) ? edata[k + 4] : -1;
        int s5 = (k + 5 < e) ? edata[k + 5] : -1;
        int s6 = (k + 6 < e) ? edata[k + 6] : -1;
        int s7 = (k + 7 < e) ? edata[k + 7] : -1;
        uint4 q0, q1, q2, q3, q4, q5, q6, q7;
        q0 = *(const uint4*)(eb + ((size_t)s0 << 6));
        if (s1 >= 0) q1 = *(const uint4*)(eb + ((size_t)s1 << 6));
        if (s2 >= 0) q2 = *(const uint4*)(eb + ((size_t)s2 << 6));
        if (s3 >= 0) q3 = *(const uint4*)(eb + ((size_t)s3 << 6));
        if (s4 >= 0) q4 = *(const uint4*)(eb + ((size_t)s4 << 6));
        if (s5 >= 0) q5 = *(const uint4*)(eb + ((size_t)s5 << 6));
        if (s6 >= 0) q6 = *(const uint4*)(eb + ((size_t)s6 << 6));
        if (s7 >= 0) q7 = *(const uint4*)(eb + ((size_t)s7 << 6));
        acc8(a0, q0);
        if (s1 >= 0) acc8(a1, q1);
        if (s2 >= 0) acc8(a0, q2);
        if (s3 >= 0) acc8(a1, q3);
        if (s4 >= 0) acc8(a0, q4);
        if (s5 >= 0) acc8(a1, q5);
        if (s6 >= 0) acc8(a0, q6);
        if (s7 >= 0) acc8(a1, q7);
    }

    float acc[8];
#pragma unroll
    for (int j = 0; j < 8; ++j) acc[j] = a0[j] + a1[j];

    float dc = dis[dest];
    size_t o = ((size_t)dest << 6) + dimo;
    if (FINAL) {
        float rd = (dc > 0.0f) ? 1.0f / dc : 0.0f;  // emb1 = z * rd
        f32x4 xa = __builtin_nontemporal_load((const f32x4*)(x + o));
        f32x4 xc = __builtin_nontemporal_load((const f32x4*)(x + o) + 1);
        uint4 qz = *(const uint4*)(embb + o);  // own z (bf16), L2-hot
        const float k3 = 1.0f / 3.0f;
        f32x4 r0, r1;
        r0.x = (xa.x + bf_lo(qz.x) * rd + dc * acc[0]) * k3;
        r0.y = (xa.y + bf_hi(qz.x) * rd + dc * acc[1]) * k3;
        r0.z = (xa.z + bf_lo(qz.y) * rd + dc * acc[2]) * k3;
        r0.w = (xa.w + bf_hi(qz.y) * rd + dc * acc[3]) * k3;
        r1.x = (xc.x + bf_lo(qz.z) * rd + dc * acc[4]) * k3;
        r1.y = (xc.y + bf_hi(qz.z) * rd + dc * acc[5]) * k3;
        r1.z = (xc.z + bf_lo(qz.w) * rd + dc * acc[6]) * k3;
        r1.w = (xc.w + bf_hi(qz.w) * rd + dc * acc[7]) * k3;
        __builtin_nontemporal_store(r0, (f32x4*)(outf + o));
        __builtin_nontemporal_store(r1, (f32x4*)(outf + o) + 1);
    } else {
        float zs = dc * dc;  // z = dis^2 * acc
        uint4 q;
        q.x = f2bf(zs * acc[0]) | (f2bf(zs * acc[1]) << 16);
        q.y = f2bf(zs * acc[2]) | (f2bf(zs * acc[3]) << 16);
        q.z = f2bf(zs * acc[4]) | (f2bf(zs * acc[5]) << 16);
        q.w = f2bf(zs * acc[6]) | (f2bf(zs * acc[7]) << 16);
        *(uint4*)(outb + o) = q;  // reused next layer: keep cached
    }
}

extern "C" void kernel_launch(void* const* d_in, const int* in_sizes, int n_in,
                              void* d_out, int out_size, void* d_ws, size_t ws_size,
                              hipStream_t stream) {
    const float* x  = (const float*)d_in[0];
    const int*   ei = (const int*)d_in[1];
    const int E = in_sizes[1] / 2;
    const int N = in_sizes[0] / EMB_DIM;  // 150000

    const int* rows = ei;       // edge_index[0]
    const int* cols = ei + E;   // edge_index[1]

    // Workspace layout (ints):
    //   gws[0] = guard 0; degoff = gws+1 (N used, NPAD region)
    //   bsum[512]
    //   dis[NPAD floats]
    //   edata[E]
    //   yb[N*64 bf16]  zb[N*64 bf16]
    int*   gws    = (int*)d_ws;
    int*   degoff = gws + 1;
    int*   bsum   = gws + NPAD;
    float* dis    = (float*)(gws + NPAD + 512);
    int*   edata  = gws + NPAD + 512 + NPAD;
    unsigned short* yb = (unsigned short*)(edata + E);
    unsigned short* zb = yb + (size_t)N * EMB_DIM;
    float* out = (float*)d_out;

    const int nblk = (N + 1023) >> 10;  // 147

    hipMemsetAsync(gws, 0, (size_t)(N + 1) * sizeof(int), stream);
    deg_kernel<<<1024, 256, 0, stream>>>(cols, degoff, E);
    scan_block<<<nblk, 1024, 0, stream>>>(degoff, bsum, dis, x, yb, N);
    scan_top<<<1, 1024, 0, stream>>>(bsum, nblk);
    add_base<<<nblk, 1024, 0, stream>>>(degoff, bsum, N);
    scatter_kernel<<<1024, 256, 0, stream>>>(rows, cols, degoff, edata, E);

    int agg_waves = (N + 7) / 8;                 // 8 dests per wave
    int agg_blocks = (agg_waves + 3) / 4;        // 4 waves per 256-thread block
    // layer 1: yb -> zb (= dis^2 * sum y)
    agg_kernel<false><<<agg_blocks, 256, 0, stream>>>(yb, edata, degoff, dis,
                                                      nullptr, zb, nullptr, N);
    // layer 2 + final: out = (x + zb/dis + dis*sum zb[src]) / 3
    agg_kernel<true><<<agg_blocks, 256, 0, stream>>>(zb, edata, degoff, dis,
                                                     x, nullptr, out, N);
}

// Round 5
// 317.707 us; speedup vs baseline: 2.3025x; 2.3025x over previous
//
#include <hip/hip_runtime.h>
#include <hip/hip_bf16.h>

// SimGCL / LightGCN 2-layer propagation — round 10.
//   r9 post-mortem: direct CSR scatter = 15x write amplification (247MB
//   for 16MB edata), 344us, pure latency. Random 4B scatters are fatal.
//   r10 = r7b partition (512-wide buckets) + r8 agg (8-deep MLP), with
//   fused_scatter rebuilt as LDS-SORTED partition:
//     hist -> LDS scan -> global reserve -> rank into bucket-ordered
//     LDS buffer (sbuf 32KB + bucket-id sbkt 16KB) -> linear writeout.
//   Wave stores now cover contiguous 112B bucket runs (~6 lines/wave vs
//   ~64 before). 59KB LDS -> 2 blocks/CU = 32 waves (full occupancy).
//   Algebra (r4): y = dis*x (bf16); z[c] = dis[c]^2 * sum y[src];
//   out = (x + z/dis + dis * sum z[src]) / 3. No per-edge weights stored.

#define EMB_DIM 64
#define BUCKET_BITS 9
#define BUCKET_SZ 512
#define EPB 8192     // edges per partition block
#define NBMAX 512    // LDS capacity for bucket counters (NB = 293 actual)
#define CAP 16384    // per-bucket pairs capacity (mean 13651, sigma 117)
#define GSTRIDE 16   // 64B stride for gcur counters (atomic-line padding)

typedef float f32x4 __attribute__((ext_vector_type(4)));

__device__ __forceinline__ float bf_lo(unsigned int q) { return __uint_as_float(q << 16); }
__device__ __forceinline__ float bf_hi(unsigned int q) { return __uint_as_float(q & 0xffff0000u); }
__device__ __forceinline__ unsigned int f2bf(float f) {  // RNE
    unsigned int u = __float_as_uint(f);
    return (u + 0x7fffu + ((u >> 16) & 1u)) >> 16;
}

// (0) init per-bucket cursors to region starts
__global__ void init_kernel(int* __restrict__ gcur, int NB) {
    int t = threadIdx.x;
    if (t < NB) gcur[t * GSTRIDE] = t * CAP;
}

// (1) fused partition: hist -> scan -> reserve -> LDS bucket-sort ->
//     coalesced writeout. 1024 threads, 8 edges each.
__global__ void fused_scatter(const int* __restrict__ rows,
                              const int* __restrict__ cols,
                              int* __restrict__ gcur,
                              unsigned int* __restrict__ pairs,
                              int E, int NB) {
    __shared__ unsigned int sbuf[EPB];       // 32KB bucket-ordered pairs
    __shared__ unsigned short sbkt[EPB];     // 16KB bucket id per slot
    __shared__ int lh[NBMAX];                // per-bucket counts
    __shared__ int lexc[NBMAX];              // local exclusive offsets
    __shared__ int lbase[NBMAX];             // global region bases
    __shared__ int lrank[NBMAX];             // rank cursors
    __shared__ int sc[NBMAX];                // scan temp
    int blk = blockIdx.x, t = threadIdx.x;
    for (int b = t; b < NBMAX; b += 1024) lh[b] = 0;
    __syncthreads();
    int start = blk * EPB, end = min(start + EPB, E);
    int nloc = end - start;
    int myc[8], myr[8];
#pragma unroll
    for (int j = 0; j < 8; ++j) {
        int i = start + t + j * 1024;
        if (i < end) {
            myc[j] = cols[i];
            myr[j] = rows[i];
            atomicAdd(&lh[myc[j] >> BUCKET_BITS], 1);
        } else {
            myc[j] = -1;
        }
    }
    __syncthreads();
    // exclusive scan of lh over NBMAX entries (512 threads active)
    if (t < NBMAX) sc[t] = lh[t];
    __syncthreads();
    for (int off = 1; off < NBMAX; off <<= 1) {
        int u = (t >= off && t < NBMAX) ? sc[t - off] : 0;
        __syncthreads();
        if (t < NBMAX) sc[t] += u;
        __syncthreads();
    }
    if (t < NBMAX) lexc[t] = sc[t] - lh[t];
    // global reserve + zero ranks
    if (t < NB) {
        int c = lh[t];
        lbase[t] = c ? atomicAdd(&gcur[t * GSTRIDE], c) : 0;
        lrank[t] = 0;
    }
    __syncthreads();
    // place edges bucket-sorted into LDS
#pragma unroll
    for (int j = 0; j < 8; ++j) {
        if (myc[j] >= 0) {
            int b = myc[j] >> BUCKET_BITS;
            int rk = atomicAdd(&lrank[b], 1);
            int p = lexc[b] + rk;
            sbuf[p] = (unsigned)myr[j] |
                      ((unsigned)(myc[j] & (BUCKET_SZ - 1)) << 18);
            sbkt[p] = (unsigned short)b;
        }
    }
    __syncthreads();
    // linear writeout: consecutive threads -> consecutive addresses
    // within each bucket run (mean run 112B).
    for (int p = t; p < nloc; p += 1024) {
        int b = sbkt[p];
        pairs[lbase[b] + (p - lexc[b])] = sbuf[p];
    }
}

// (2) scan bucket counts (NB <= 512) -> gbase (exclusive, for edata);
//     also offsets[N] = E.
__global__ void count_scan(const int* __restrict__ gcur,
                           int* __restrict__ gbase,
                           int* __restrict__ offsets, int NB, int N, int E) {
    __shared__ int lds[NBMAX];
    int t = threadIdx.x;
    int v = (t < NB) ? (gcur[t * GSTRIDE] - t * CAP) : 0;
    lds[t] = v;
    __syncthreads();
    for (int off = 1; off < NBMAX; off <<= 1) {
        int u = (t >= off) ? lds[t - off] : 0;
        __syncthreads();
        lds[t] += u;
        __syncthreads();
    }
    if (t < NB) gbase[t] = lds[t] - v;
    if (t == 0) offsets[N] = E;
}

// (3) per-bucket finalize: counting sort by col; emits dis[], offsets[],
//     col-sorted src -> edata; fused y = dis*x -> bf16 for bucket's rows.
__global__ void bucket_finalize(const unsigned int* __restrict__ pairs,
                                const int* __restrict__ gcur,
                                const int* __restrict__ gbase,
                                const float* __restrict__ x,
                                int* __restrict__ edata,
                                int* __restrict__ offsets,
                                float* __restrict__ dis,
                                unsigned short* __restrict__ yb,
                                int N, int E, int NB) {
    __shared__ int ccnt[BUCKET_SZ];
    __shared__ int cexc[BUCKET_SZ];
    __shared__ int sc[1024];
    int b = blockIdx.x, t = threadIdx.x;
    int pbase = b * CAP;
    int cnt = gcur[b * GSTRIDE] - pbase;
    int base = gbase[b];
    int col0 = b << BUCKET_BITS;
    int ncols = min(BUCKET_SZ, N - col0);

    if (t < BUCKET_SZ) ccnt[t] = 0;
    __syncthreads();
    for (int i = t; i < cnt; i += blockDim.x)
        atomicAdd(&ccnt[pairs[pbase + i] >> 18], 1);
    __syncthreads();

    int v = (t < BUCKET_SZ) ? ccnt[t] : 0;
    sc[t] = v;
    __syncthreads();
    for (int off = 1; off < 1024; off <<= 1) {
        int u = (t >= off) ? sc[t - off] : 0;
        __syncthreads();
        sc[t] += u;
        __syncthreads();
    }
    if (t < BUCKET_SZ) cexc[t] = sc[t] - v;
    __syncthreads();

    if (t < ncols) {
        int c = ccnt[t];
        offsets[col0 + t] = base + cexc[t];
        dis[col0 + t] = (c > 0) ? rsqrtf((float)c) : 0.0f;
    }
    // reuse sc[0..511] as rank counters
    if (t < BUCKET_SZ) sc[t] = 0;
    __syncthreads();
    for (int i = t; i < cnt; i += blockDim.x) {
        unsigned p = pairs[pbase + i];
        int lc = p >> 18;
        int src = p & 0x3FFFF;
        int rk = atomicAdd(&sc[lc], 1);
        edata[base + cexc[lc] + rk] = src;
    }

    // fused: y[row] = dis[row] * x[row] in bf16 (ccnt stable).
    for (int u = t; u < ncols * 16; u += blockDim.x) {
        int lr = u >> 4;
        int part = u & 15;
        int c = ccnt[lr];
        float d = (c > 0) ? rsqrtf((float)c) : 0.0f;
        size_t o = (((size_t)(col0 + lr)) << 6) + part * 4;
        float4 vx = *(const float4*)(x + o);
        uint2 w;
        w.x = f2bf(vx.x * d) | (f2bf(vx.y * d) << 16);
        w.y = f2bf(vx.z * d) | (f2bf(vx.w * d) << 16);
        *(uint2*)(yb + o) = w;
    }
}

__device__ __forceinline__ void acc8(float* acc, uint4 q) {
    acc[0] += bf_lo(q.x);
    acc[1] += bf_hi(q.x);
    acc[2] += bf_lo(q.y);
    acc[3] += bf_hi(q.y);
    acc[4] += bf_lo(q.z);
    acc[5] += bf_hi(q.z);
    acc[6] += bf_lo(q.w);
    acc[7] += bf_hi(q.w);
}

// Wave = 8 subgroups x 8 lanes; each SUB owns ONE destination node
// (8 dests per wave). Lane holds 8 fp32 dims. Hot loop = 8 edges in
// flight per sub (64 gathers outstanding per wave), dual accumulators.
// !FINAL (embb = yb):  zb[c] = bf16( dis[c]^2 * acc )
//  FINAL (embb = zb):  out = (x + zb/dis + dis*acc)/3
template <bool FINAL>
__global__ void agg_kernel(const unsigned short* __restrict__ embb,
                           const int* __restrict__ edata,
                           const int* __restrict__ offsets,
                           const float* __restrict__ dis,
                           const float* __restrict__ x,        // FINAL only
                           unsigned short* __restrict__ outb,  // !FINAL
                           float* __restrict__ outf,           // FINAL
                           int n) {
    int wave = (blockIdx.x * blockDim.x + threadIdx.x) >> 6;
    int lane = threadIdx.x & 63;
    int sub = lane >> 3;
    int dest = (wave << 3) + sub;
    if (dest >= n) return;
    int dimo = (lane & 7) * 8;

    int s = offsets[dest];
    int e = offsets[dest + 1];

    float a0[8] = {0, 0, 0, 0, 0, 0, 0, 0};
    float a1[8] = {0, 0, 0, 0, 0, 0, 0, 0};
    const unsigned short* eb = embb + dimo;

    int k = s;
    int kfull = s + ((e - s) & ~7);
    for (; k < kfull; k += 8) {
        int s0 = edata[k];
        int s1 = edata[k + 1];
        int s2 = edata[k + 2];
        int s3 = edata[k + 3];
        int s4 = edata[k + 4];
        int s5 = edata[k + 5];
        int s6 = edata[k + 6];
        int s7 = edata[k + 7];
        uint4 q0 = *(const uint4*)(eb + ((size_t)s0 << 6));
        uint4 q1 = *(const uint4*)(eb + ((size_t)s1 << 6));
        uint4 q2 = *(const uint4*)(eb + ((size_t)s2 << 6));
        uint4 q3 = *(const uint4*)(eb + ((size_t)s3 << 6));
        uint4 q4 = *(const uint4*)(eb + ((size_t)s4 << 6));
        uint4 q5 = *(const uint4*)(eb + ((size_t)s5 << 6));
        uint4 q6 = *(const uint4*)(eb + ((size_t)s6 << 6));
        uint4 q7 = *(const uint4*)(eb + ((size_t)s7 << 6));
        acc8(a0, q0);
        acc8(a1, q1);
        acc8(a0, q2);
        acc8(a1, q3);
        acc8(a0, q4);
        acc8(a1, q5);
        acc8(a0, q6);
        acc8(a1, q7);
    }
    if (k < e) {  // tail < 8
        int s0 = edata[k];
        int s1 = (k + 1 < e) ? edata[k + 1] : -1;
        int s2 = (k + 2 < e) ? edata[k + 2] : -1;
        int s3 = (k + 3 < e) ? edata[k + 3] : -1;
        int s4 = (k + 4 < e) ? edata[k + 4] : -1;
        int s5 = (k + 5 < e) ? edata[k + 5] : -1;
        int s6 = (k + 6 < e) ? edata[k + 6] : -1;
        int s7 = (k + 7 < e) ? edata[k + 7] : -1;
        uint4 q0, q1, q2, q3, q4, q5, q6, q7;
        q0 = *(const uint4*)(eb + ((size_t)s0 << 6));
        if (s1 >= 0) q1 = *(const uint4*)(eb + ((size_t)s1 << 6));
        if (s2 >= 0) q2 = *(const uint4*)(eb + ((size_t)s2 << 6));
        if (s3 >= 0) q3 = *(const uint4*)(eb + ((size_t)s3 << 6));
        if (s4 >= 0) q4 = *(const uint4*)(eb + ((size_t)s4 << 6));
        if (s5 >= 0) q5 = *(const uint4*)(eb + ((size_t)s5 << 6));
        if (s6 >= 0) q6 = *(const uint4*)(eb + ((size_t)s6 << 6));
        if (s7 >= 0) q7 = *(const uint4*)(eb + ((size_t)s7 << 6));
        acc8(a0, q0);
        if (s1 >= 0) acc8(a1, q1);
        if (s2 >= 0) acc8(a0, q2);
        if (s3 >= 0) acc8(a1, q3);
        if (s4 >= 0) acc8(a0, q4);
        if (s5 >= 0) acc8(a1, q5);
        if (s6 >= 0) acc8(a0, q6);
        if (s7 >= 0) acc8(a1, q7);
    }

    float acc[8];
#pragma unroll
    for (int j = 0; j < 8; ++j) acc[j] = a0[j] + a1[j];

    float dc = dis[dest];
    size_t o = ((size_t)dest << 6) + dimo;
    if (FINAL) {
        float rd = (dc > 0.0f) ? 1.0f / dc : 0.0f;  // emb1 = z * rd
        f32x4 xa = __builtin_nontemporal_load((const f32x4*)(x + o));
        f32x4 xc = __builtin_nontemporal_load((const f32x4*)(x + o) + 1);
        uint4 qz = *(const uint4*)(embb + o);  // own z (bf16), L2-hot
        const float k3 = 1.0f / 3.0f;
        f32x4 r0, r1;
        r0.x = (xa.x + bf_lo(qz.x) * rd + dc * acc[0]) * k3;
        r0.y = (xa.y + bf_hi(qz.x) * rd + dc * acc[1]) * k3;
        r0.z = (xa.z + bf_lo(qz.y) * rd + dc * acc[2]) * k3;
        r0.w = (xa.w + bf_hi(qz.y) * rd + dc * acc[3]) * k3;
        r1.x = (xc.x + bf_lo(qz.z) * rd + dc * acc[4]) * k3;
        r1.y = (xc.y + bf_hi(qz.z) * rd + dc * acc[5]) * k3;
        r1.z = (xc.z + bf_lo(qz.w) * rd + dc * acc[6]) * k3;
        r1.w = (xc.w + bf_hi(qz.w) * rd + dc * acc[7]) * k3;
        __builtin_nontemporal_store(r0, (f32x4*)(outf + o));
        __builtin_nontemporal_store(r1, (f32x4*)(outf + o) + 1);
    } else {
        float zs = dc * dc;  // z = dis^2 * acc
        uint4 q;
        q.x = f2bf(zs * acc[0]) | (f2bf(zs * acc[1]) << 16);
        q.y = f2bf(zs * acc[2]) | (f2bf(zs * acc[3]) << 16);
        q.z = f2bf(zs * acc[4]) | (f2bf(zs * acc[5]) << 16);
        q.w = f2bf(zs * acc[6]) | (f2bf(zs * acc[7]) << 16);
        *(uint4*)(outb + o) = q;  // reused next layer: keep cached
    }
}

extern "C" void kernel_launch(void* const* d_in, const int* in_sizes, int n_in,
                              void* d_out, int out_size, void* d_ws, size_t ws_size,
                              hipStream_t stream) {
    const float* x  = (const float*)d_in[0];
    const int*   ei = (const int*)d_in[1];
    const int E = in_sizes[1] / 2;
    const int N = in_sizes[0] / EMB_DIM;  // 150000

    const int* rows = ei;       // edge_index[0]
    const int* cols = ei + E;   // edge_index[1]

    const int NB = (N + BUCKET_SZ - 1) >> BUCKET_BITS;  // 293
    const int NBLK = (E + EPB - 1) / EPB;               // 489

    // Workspace layout (ints):
    //   gcur[512*GSTRIDE] gbase[512]
    //   dis[150080] offsets[150080] edata[E]
    //   yb[N*64 bf16] = 4.8M ints
    //   region R: zb[N*64 bf16] overlapped by pairs[NB*CAP] (dead before agg1)
    int*   gcur    = (int*)d_ws;
    int*   gbase   = gcur + 512 * GSTRIDE;
    float* dis     = (float*)(gbase + 512);
    int*   offsets = (int*)(dis + 150080);
    int*   edata   = offsets + 150080;
    unsigned short* yb = (unsigned short*)(edata + E);
    unsigned short* zb = yb + (size_t)N * EMB_DIM;
    unsigned int* pairs = (unsigned int*)zb;  // lifetime: fused_scatter..finalize
    float* out = (float*)d_out;

    init_kernel<<<1, 512, 0, stream>>>(gcur, NB);
    fused_scatter<<<NBLK, 1024, 0, stream>>>(rows, cols, gcur, pairs, E, NB);
    count_scan<<<1, 512, 0, stream>>>(gcur, gbase, offsets, NB, N, E);
    bucket_finalize<<<NB, 1024, 0, stream>>>(pairs, gcur, gbase, x, edata,
                                             offsets, dis, yb, N, E, NB);

    int agg_waves = (N + 7) / 8;                 // 8 dests per wave
    int agg_blocks = (agg_waves + 3) / 4;        // 4 waves per 256-thread block
    // layer 1: yb -> zb (= dis^2 * sum y)
    agg_kernel<false><<<agg_blocks, 256, 0, stream>>>(yb, edata, offsets, dis,
                                                      nullptr, zb, nullptr, N);
    // layer 2 + final: out = (x + zb/dis + dis*sum zb[src]) / 3
    agg_kernel<true><<<agg_blocks, 256, 0, stream>>>(zb, edata, offsets, dis,
                                                     x, nullptr, out, N);
}

// Round 6
// 299.829 us; speedup vs baseline: 2.4397x; 1.0596x over previous
//
#include <hip/hip_runtime.h>
#include <hip/hip_bf16.h>

// SimGCL / LightGCN 2-layer propagation — round 11.
//   r10 post-mortem: agg now 77.4us each (near random-gather structural
//   floor: 512MB demand, 19.2MB table, per-XCD 4MB L2, 3.8TB/s fill).
//   Partition is the slack: ~162us vs ~25us streaming floor.
//   r10 -> r11 (partition only):
//   - yb (y = dis*x -> bf16) moved out of bucket_finalize's 293-block
//     tail (57% packing) into a flat grid-stride kernel (perfect balance).
//   - count_scan kernel deleted: each finalize block computes gbase via
//     a wave reduction over the 293 bucket counts (L2-hot); offsets[N]=E
//     moved into init. One fewer launch + dependency.
//   - Both 512-entry Hillis-Steele LDS scans (18 barriers) replaced with
//     shfl wave-scans (3 barriers).
//   Algebra (r4): y = dis*x (bf16); z[c] = dis[c]^2 * sum y[src];
//   out = (x + z/dis + dis * sum z[src]) / 3. No per-edge weights stored.

#define EMB_DIM 64
#define BUCKET_BITS 9
#define BUCKET_SZ 512
#define EPB 8192     // edges per partition block
#define NBMAX 512    // LDS capacity for bucket counters (NB = 293 actual)
#define CAP 16384    // per-bucket pairs capacity (mean 13651, sigma 117)
#define GSTRIDE 16   // 64B stride for gcur counters (atomic-line padding)

typedef float f32x4 __attribute__((ext_vector_type(4)));

__device__ __forceinline__ float bf_lo(unsigned int q) { return __uint_as_float(q << 16); }
__device__ __forceinline__ float bf_hi(unsigned int q) { return __uint_as_float(q & 0xffff0000u); }
__device__ __forceinline__ unsigned int f2bf(float f) {  // RNE
    unsigned int u = __float_as_uint(f);
    return (u + 0x7fffu + ((u >> 16) & 1u)) >> 16;
}

// (0) init per-bucket cursors to region starts; offsets[N] = E guard.
__global__ void init_kernel(int* __restrict__ gcur, int* __restrict__ offsets,
                            int NB, int N, int E) {
    int t = threadIdx.x;
    if (t < NB) gcur[t * GSTRIDE] = t * CAP;
    if (t == 0) offsets[N] = E;
}

// (1) fused partition: hist -> wave-scan -> reserve -> LDS bucket-sort ->
//     coalesced writeout. 1024 threads, 8 edges each.
__global__ void fused_scatter(const int* __restrict__ rows,
                              const int* __restrict__ cols,
                              int* __restrict__ gcur,
                              unsigned int* __restrict__ pairs,
                              int E, int NB) {
    __shared__ unsigned int sbuf[EPB];       // 32KB bucket-ordered pairs
    __shared__ unsigned short sbkt[EPB];     // 16KB bucket id per slot
    __shared__ int lh[NBMAX];                // per-bucket counts
    __shared__ int lexc[NBMAX];              // local exclusive offsets
    __shared__ int lbase[NBMAX];             // global region bases
    __shared__ int lrank[NBMAX];             // rank cursors
    __shared__ int wsum[8];                  // wave-scan partials
    int blk = blockIdx.x, t = threadIdx.x;
    for (int b = t; b < NBMAX; b += 1024) lh[b] = 0;
    __syncthreads();
    int start = blk * EPB, end = min(start + EPB, E);
    int nloc = end - start;
    int myc[8], myr[8];
#pragma unroll
    for (int j = 0; j < 8; ++j) {
        int i = start + t + j * 1024;
        if (i < end) {
            myc[j] = cols[i];
            myr[j] = rows[i];
            atomicAdd(&lh[myc[j] >> BUCKET_BITS], 1);
        } else {
            myc[j] = -1;
        }
    }
    __syncthreads();
    // wave-scan of lh[0..511]: waves 0-7 scan 64 entries each via shfl.
    int v = 0, incl = 0;
    if (t < 512) {
        v = lh[t];
        incl = v;
        int lane = t & 63;
#pragma unroll
        for (int off = 1; off < 64; off <<= 1) {
            int u = __shfl_up(incl, off, 64);
            if (lane >= off) incl += u;
        }
        if (lane == 63) wsum[t >> 6] = incl;
    }
    __syncthreads();
    if (t < 8) {  // lanes 0..7 of wave 0: exclusive scan of 8 wave sums
        int s = wsum[t];
        int inc2 = s;
#pragma unroll
        for (int off = 1; off < 8; off <<= 1) {
            int u = __shfl_up(inc2, off, 64);
            if (t >= off) inc2 += u;
        }
        wsum[t] = inc2 - s;
    }
    __syncthreads();
    if (t < 512) lexc[t] = (incl - v) + wsum[t >> 6];
    // global reserve + zero ranks
    if (t < NB) {
        int c = lh[t];
        lbase[t] = c ? atomicAdd(&gcur[t * GSTRIDE], c) : 0;
        lrank[t] = 0;
    }
    __syncthreads();
    // place edges bucket-sorted into LDS
#pragma unroll
    for (int j = 0; j < 8; ++j) {
        if (myc[j] >= 0) {
            int b = myc[j] >> BUCKET_BITS;
            int rk = atomicAdd(&lrank[b], 1);
            int p = lexc[b] + rk;
            sbuf[p] = (unsigned)myr[j] |
                      ((unsigned)(myc[j] & (BUCKET_SZ - 1)) << 18);
            sbkt[p] = (unsigned short)b;
        }
    }
    __syncthreads();
    // linear writeout: consecutive threads -> consecutive addresses
    // within each bucket run (mean run 112B).
    for (int p = t; p < nloc; p += 1024) {
        int b = sbkt[p];
        pairs[lbase[b] + (p - lexc[b])] = sbuf[p];
    }
}

// (2) per-bucket finalize: inline gbase reduction; counting sort by col;
//     emits offsets[], dis[], col-sorted src -> edata. (yb moved out.)
__global__ void bucket_finalize(const unsigned int* __restrict__ pairs,
                                const int* __restrict__ gcur,
                                int* __restrict__ edata,
                                int* __restrict__ offsets,
                                float* __restrict__ dis,
                                int N, int E, int NB) {
    __shared__ int ccnt[BUCKET_SZ];
    __shared__ int cexc[BUCKET_SZ];
    __shared__ int rnk[BUCKET_SZ];
    __shared__ int wsum[16];
    __shared__ int gb_s;
    int b = blockIdx.x, t = threadIdx.x;
    int pbase = b * CAP;
    int cnt = gcur[b * GSTRIDE] - pbase;

    // gbase = sum of counts of buckets before b (L2-hot reads)
    int part = 0;
    for (int j = t; j < b; j += 1024) part += gcur[j * GSTRIDE] - j * CAP;
#pragma unroll
    for (int off = 32; off; off >>= 1) part += __shfl_down(part, off, 64);
    if ((t & 63) == 0) wsum[t >> 6] = part;
    if (t < BUCKET_SZ) ccnt[t] = 0;
    __syncthreads();
    if (t == 0) {
        int g = 0;
#pragma unroll
        for (int w = 0; w < 16; ++w) g += wsum[w];
        gb_s = g;
    }
    // hist (concurrent with t==0's gbase finish; wsum untouched here)
    for (int i = t; i < cnt; i += 1024)
        atomicAdd(&ccnt[pairs[pbase + i] >> 18], 1);
    __syncthreads();

    // wave-scan ccnt[0..511] -> cexc (exclusive)
    int v = 0, incl = 0;
    if (t < 512) {
        v = ccnt[t];
        incl = v;
        int lane = t & 63;
#pragma unroll
        for (int off = 1; off < 64; off <<= 1) {
            int u = __shfl_up(incl, off, 64);
            if (lane >= off) incl += u;
        }
        if (lane == 63) wsum[t >> 6] = incl;
    }
    __syncthreads();
    if (t < 8) {
        int s = wsum[t];
        int inc2 = s;
#pragma unroll
        for (int off = 1; off < 8; off <<= 1) {
            int u = __shfl_up(inc2, off, 64);
            if (t >= off) inc2 += u;
        }
        wsum[t] = inc2 - s;
    }
    __syncthreads();
    if (t < 512) cexc[t] = (incl - v) + wsum[t >> 6];
    if (t < BUCKET_SZ) rnk[t] = 0;
    __syncthreads();

    int base = gb_s;
    int col0 = b << BUCKET_BITS;
    int ncols = min(BUCKET_SZ, N - col0);
    if (t < ncols) {
        int c = ccnt[t];
        offsets[col0 + t] = base + cexc[t];
        dis[col0 + t] = (c > 0) ? rsqrtf((float)c) : 0.0f;
    }
    __syncthreads();
    for (int i = t; i < cnt; i += 1024) {
        unsigned p = pairs[pbase + i];  // L2-hot re-read
        int lc = p >> 18;
        int src = p & 0x3FFFF;
        int rk = atomicAdd(&rnk[lc], 1);
        edata[base + cexc[lc] + rk] = src;
    }
}

// (3) flat streaming: y[row] = dis[row] * x[row] -> bf16. Perfect balance.
__global__ void yb_kernel(const float* __restrict__ x,
                          const float* __restrict__ dis,
                          unsigned short* __restrict__ yb, int N) {
    int tid = blockIdx.x * blockDim.x + threadIdx.x;
    int nth = gridDim.x * blockDim.x;
    int total = N * 16;
    for (int u = tid; u < total; u += nth) {
        int lr = u >> 4;
        int part = u & 15;
        float d = dis[lr];
        size_t o = (((size_t)lr) << 6) + part * 4;
        float4 vx = *(const float4*)(x + o);
        uint2 w;
        w.x = f2bf(vx.x * d) | (f2bf(vx.y * d) << 16);
        w.y = f2bf(vx.z * d) | (f2bf(vx.w * d) << 16);
        *(uint2*)(yb + o) = w;
    }
}

__device__ __forceinline__ void acc8(float* acc, uint4 q) {
    acc[0] += bf_lo(q.x);
    acc[1] += bf_hi(q.x);
    acc[2] += bf_lo(q.y);
    acc[3] += bf_hi(q.y);
    acc[4] += bf_lo(q.z);
    acc[5] += bf_hi(q.z);
    acc[6] += bf_lo(q.w);
    acc[7] += bf_hi(q.w);
}

// Wave = 8 subgroups x 8 lanes; each SUB owns ONE destination node
// (8 dests per wave). Lane holds 8 fp32 dims. Hot loop = 8 edges in
// flight per sub (64 gathers outstanding per wave), dual accumulators.
// !FINAL (embb = yb):  zb[c] = bf16( dis[c]^2 * acc )
//  FINAL (embb = zb):  out = (x + zb/dis + dis*acc)/3
template <bool FINAL>
__global__ void agg_kernel(const unsigned short* __restrict__ embb,
                           const int* __restrict__ edata,
                           const int* __restrict__ offsets,
                           const float* __restrict__ dis,
                           const float* __restrict__ x,        // FINAL only
                           unsigned short* __restrict__ outb,  // !FINAL
                           float* __restrict__ outf,           // FINAL
                           int n) {
    int wave = (blockIdx.x * blockDim.x + threadIdx.x) >> 6;
    int lane = threadIdx.x & 63;
    int sub = lane >> 3;
    int dest = (wave << 3) + sub;
    if (dest >= n) return;
    int dimo = (lane & 7) * 8;

    int s = offsets[dest];
    int e = offsets[dest + 1];

    float a0[8] = {0, 0, 0, 0, 0, 0, 0, 0};
    float a1[8] = {0, 0, 0, 0, 0, 0, 0, 0};
    const unsigned short* eb = embb + dimo;

    int k = s;
    int kfull = s + ((e - s) & ~7);
    for (; k < kfull; k += 8) {
        int s0 = edata[k];
        int s1 = edata[k + 1];
        int s2 = edata[k + 2];
        int s3 = edata[k + 3];
        int s4 = edata[k + 4];
        int s5 = edata[k + 5];
        int s6 = edata[k + 6];
        int s7 = edata[k + 7];
        uint4 q0 = *(const uint4*)(eb + ((size_t)s0 << 6));
        uint4 q1 = *(const uint4*)(eb + ((size_t)s1 << 6));
        uint4 q2 = *(const uint4*)(eb + ((size_t)s2 << 6));
        uint4 q3 = *(const uint4*)(eb + ((size_t)s3 << 6));
        uint4 q4 = *(const uint4*)(eb + ((size_t)s4 << 6));
        uint4 q5 = *(const uint4*)(eb + ((size_t)s5 << 6));
        uint4 q6 = *(const uint4*)(eb + ((size_t)s6 << 6));
        uint4 q7 = *(const uint4*)(eb + ((size_t)s7 << 6));
        acc8(a0, q0);
        acc8(a1, q1);
        acc8(a0, q2);
        acc8(a1, q3);
        acc8(a0, q4);
        acc8(a1, q5);
        acc8(a0, q6);
        acc8(a1, q7);
    }
    if (k < e) {  // tail < 8
        int s0 = edata[k];
        int s1 = (k + 1 < e) ? edata[k + 1] : -1;
        int s2 = (k + 2 < e) ? edata[k + 2] : -1;
        int s3 = (k + 3 < e) ? edata[k + 3] : -1;
        int s4 = (k + 4 < e) ? edata[k + 4] : -1;
        int s5 = (k + 5 < e) ? edata[k + 5] : -1;
        int s6 = (k + 6 < e) ? edata[k + 6] : -1;
        int s7 = (k + 7 < e) ? edata[k + 7] : -1;
        uint4 q0, q1, q2, q3, q4, q5, q6, q7;
        q0 = *(const uint4*)(eb + ((size_t)s0 << 6));
        if (s1 >= 0) q1 = *(const uint4*)(eb + ((size_t)s1 << 6));
        if (s2 >= 0) q2 = *(const uint4*)(eb + ((size_t)s2 << 6));
        if (s3 >= 0) q3 = *(const uint4*)(eb + ((size_t)s3 << 6));
        if (s4 >= 0) q4 = *(const uint4*)(eb + ((size_t)s4 << 6));
        if (s5 >= 0) q5 = *(const uint4*)(eb + ((size_t)s5 << 6));
        if (s6 >= 0) q6 = *(const uint4*)(eb + ((size_t)s6 << 6));
        if (s7 >= 0) q7 = *(const uint4*)(eb + ((size_t)s7 << 6));
        acc8(a0, q0);
        if (s1 >= 0) acc8(a1, q1);
        if (s2 >= 0) acc8(a0, q2);
        if (s3 >= 0) acc8(a1, q3);
        if (s4 >= 0) acc8(a0, q4);
        if (s5 >= 0) acc8(a1, q5);
        if (s6 >= 0) acc8(a0, q6);
        if (s7 >= 0) acc8(a1, q7);
    }

    float acc[8];
#pragma unroll
    for (int j = 0; j < 8; ++j) acc[j] = a0[j] + a1[j];

    float dc = dis[dest];
    size_t o = ((size_t)dest << 6) + dimo;
    if (FINAL) {
        float rd = (dc > 0.0f) ? 1.0f / dc : 0.0f;  // emb1 = z * rd
        f32x4 xa = __builtin_nontemporal_load((const f32x4*)(x + o));
        f32x4 xc = __builtin_nontemporal_load((const f32x4*)(x + o) + 1);
        uint4 qz = *(const uint4*)(embb + o);  // own z (bf16), L2-hot
        const float k3 = 1.0f / 3.0f;
        f32x4 r0, r1;
        r0.x = (xa.x + bf_lo(qz.x) * rd + dc * acc[0]) * k3;
        r0.y = (xa.y + bf_hi(qz.x) * rd + dc * acc[1]) * k3;
        r0.z = (xa.z + bf_lo(qz.y) * rd + dc * acc[2]) * k3;
        r0.w = (xa.w + bf_hi(qz.y) * rd + dc * acc[3]) * k3;
        r1.x = (xc.x + bf_lo(qz.z) * rd + dc * acc[4]) * k3;
        r1.y = (xc.y + bf_hi(qz.z) * rd + dc * acc[5]) * k3;
        r1.z = (xc.z + bf_lo(qz.w) * rd + dc * acc[6]) * k3;
        r1.w = (xc.w + bf_hi(qz.w) * rd + dc * acc[7]) * k3;
        __builtin_nontemporal_store(r0, (f32x4*)(outf + o));
        __builtin_nontemporal_store(r1, (f32x4*)(outf + o) + 1);
    } else {
        float zs = dc * dc;  // z = dis^2 * acc
        uint4 q;
        q.x = f2bf(zs * acc[0]) | (f2bf(zs * acc[1]) << 16);
        q.y = f2bf(zs * acc[2]) | (f2bf(zs * acc[3]) << 16);
        q.z = f2bf(zs * acc[4]) | (f2bf(zs * acc[5]) << 16);
        q.w = f2bf(zs * acc[6]) | (f2bf(zs * acc[7]) << 16);
        *(uint4*)(outb + o) = q;  // reused next layer: keep cached
    }
}

extern "C" void kernel_launch(void* const* d_in, const int* in_sizes, int n_in,
                              void* d_out, int out_size, void* d_ws, size_t ws_size,
                              hipStream_t stream) {
    const float* x  = (const float*)d_in[0];
    const int*   ei = (const int*)d_in[1];
    const int E = in_sizes[1] / 2;
    const int N = in_sizes[0] / EMB_DIM;  // 150000

    const int* rows = ei;       // edge_index[0]
    const int* cols = ei + E;   // edge_index[1]

    const int NB = (N + BUCKET_SZ - 1) >> BUCKET_BITS;  // 293
    const int NBLK = (E + EPB - 1) / EPB;               // 489

    // Workspace layout (ints):
    //   gcur[512*GSTRIDE]
    //   dis[150080] offsets[150080] edata[E]
    //   yb[N*64 bf16] = 4.8M ints
    //   region R: zb[N*64 bf16] overlapped by pairs[NB*CAP] (dead before agg1)
    int*   gcur    = (int*)d_ws;
    float* dis     = (float*)(gcur + 512 * GSTRIDE);
    int*   offsets = (int*)(dis + 150080);
    int*   edata   = offsets + 150080;
    unsigned short* yb = (unsigned short*)(edata + E);
    unsigned short* zb = yb + (size_t)N * EMB_DIM;
    unsigned int* pairs = (unsigned int*)zb;  // lifetime: fused_scatter..finalize
    float* out = (float*)d_out;

    init_kernel<<<1, 512, 0, stream>>>(gcur, offsets, NB, N, E);
    fused_scatter<<<NBLK, 1024, 0, stream>>>(rows, cols, gcur, pairs, E, NB);
    bucket_finalize<<<NB, 1024, 0, stream>>>(pairs, gcur, edata, offsets,
                                             dis, N, E, NB);
    yb_kernel<<<2048, 256, 0, stream>>>(x, dis, yb, N);

    int agg_waves = (N + 7) / 8;                 // 8 dests per wave
    int agg_blocks = (agg_waves + 3) / 4;        // 4 waves per 256-thread block
    // layer 1: yb -> zb (= dis^2 * sum y)
    agg_kernel<false><<<agg_blocks, 256, 0, stream>>>(yb, edata, offsets, dis,
                                                      nullptr, zb, nullptr, N);
    // layer 2 + final: out = (x + zb/dis + dis*sum zb[src]) / 3
    agg_kernel<true><<<agg_blocks, 256, 0, stream>>>(zb, edata, offsets, dis,
                                                     x, nullptr, out, N);
}

// Round 7
// 281.487 us; speedup vs baseline: 2.5987x; 1.0652x over previous
//
#include <hip/hip_runtime.h>
#include <hip/hip_bf16.h>

// SimGCL / LightGCN 2-layer propagation — round 12.
//   r11 post-mortem: agg 2x78us (random-gather ceiling ~3.8TB/s, MLP not
//   the limiter); partition ~144us vs ~30us floor. Main suspect: finalize
//   pass-2's 4M scattered 4B global stores (wave -> ~60 lines).
//   r11 -> r12 (partition only):
//   - bucket_finalize: counting-sort INTO LDS (sbuf 64KB, 2 blocks/CU),
//     then perfectly-coalesced linear writeout to edata. Scattered global
//     stores -> LDS writes (~2-4-way bank, free) + streaming stores.
//   - fused_scatter: ldiff[] = lbase - lexc folded once per bucket; one
//     less LDS read per edge in writeout.
//   Algebra (r4): y = dis*x (bf16); z[c] = dis[c]^2 * sum y[src];
//   out = (x + z/dis + dis * sum z[src]) / 3. No per-edge weights stored.

#define EMB_DIM 64
#define BUCKET_BITS 9
#define BUCKET_SZ 512
#define EPB 8192     // edges per partition block
#define NBMAX 512    // LDS capacity for bucket counters (NB = 293 actual)
#define CAP 16384    // per-bucket pairs capacity (mean 13651, sigma 117)
#define GSTRIDE 16   // 64B stride for gcur counters (atomic-line padding)

typedef float f32x4 __attribute__((ext_vector_type(4)));

__device__ __forceinline__ float bf_lo(unsigned int q) { return __uint_as_float(q << 16); }
__device__ __forceinline__ float bf_hi(unsigned int q) { return __uint_as_float(q & 0xffff0000u); }
__device__ __forceinline__ unsigned int f2bf(float f) {  // RNE
    unsigned int u = __float_as_uint(f);
    return (u + 0x7fffu + ((u >> 16) & 1u)) >> 16;
}

// (0) init per-bucket cursors to region starts; offsets[N] = E guard.
__global__ void init_kernel(int* __restrict__ gcur, int* __restrict__ offsets,
                            int NB, int N, int E) {
    int t = threadIdx.x;
    if (t < NB) gcur[t * GSTRIDE] = t * CAP;
    if (t == 0) offsets[N] = E;
}

// (1) fused partition: hist -> wave-scan -> reserve -> LDS bucket-sort ->
//     coalesced writeout. 1024 threads, 8 edges each.
__global__ void fused_scatter(const int* __restrict__ rows,
                              const int* __restrict__ cols,
                              int* __restrict__ gcur,
                              unsigned int* __restrict__ pairs,
                              int E, int NB) {
    __shared__ unsigned int sbuf[EPB];       // 32KB bucket-ordered pairs
    __shared__ unsigned short sbkt[EPB];     // 16KB bucket id per slot
    __shared__ int lh[NBMAX];                // per-bucket counts
    __shared__ int lexc[NBMAX];              // local exclusive offsets
    __shared__ int ldiff[NBMAX];             // lbase - lexc (writeout addr)
    __shared__ int lrank[NBMAX];             // rank cursors
    __shared__ int wsum[8];                  // wave-scan partials
    int blk = blockIdx.x, t = threadIdx.x;
    for (int b = t; b < NBMAX; b += 1024) lh[b] = 0;
    __syncthreads();
    int start = blk * EPB, end = min(start + EPB, E);
    int nloc = end - start;
    int myc[8], myr[8];
#pragma unroll
    for (int j = 0; j < 8; ++j) {
        int i = start + t + j * 1024;
        if (i < end) {
            myc[j] = cols[i];
            myr[j] = rows[i];
            atomicAdd(&lh[myc[j] >> BUCKET_BITS], 1);
        } else {
            myc[j] = -1;
        }
    }
    __syncthreads();
    // wave-scan of lh[0..511]: waves 0-7 scan 64 entries each via shfl.
    int v = 0, incl = 0;
    if (t < 512) {
        v = lh[t];
        incl = v;
        int lane = t & 63;
#pragma unroll
        for (int off = 1; off < 64; off <<= 1) {
            int u = __shfl_up(incl, off, 64);
            if (lane >= off) incl += u;
        }
        if (lane == 63) wsum[t >> 6] = incl;
    }
    __syncthreads();
    if (t < 8) {  // lanes 0..7 of wave 0: exclusive scan of 8 wave sums
        int s = wsum[t];
        int inc2 = s;
#pragma unroll
        for (int off = 1; off < 8; off <<= 1) {
            int u = __shfl_up(inc2, off, 64);
            if (t >= off) inc2 += u;
        }
        wsum[t] = inc2 - s;
    }
    __syncthreads();
    int myexc = 0;
    if (t < 512) {
        myexc = (incl - v) + wsum[t >> 6];
        lexc[t] = myexc;
    }
    // global reserve + zero ranks; ldiff = gbase - lexc
    if (t < NB) {
        int c = lh[t];
        int gb = c ? atomicAdd(&gcur[t * GSTRIDE], c) : 0;
        ldiff[t] = gb - myexc;
        lrank[t] = 0;
    }
    __syncthreads();
    // place edges bucket-sorted into LDS
#pragma unroll
    for (int j = 0; j < 8; ++j) {
        if (myc[j] >= 0) {
            int b = myc[j] >> BUCKET_BITS;
            int rk = atomicAdd(&lrank[b], 1);
            int p = lexc[b] + rk;
            sbuf[p] = (unsigned)myr[j] |
                      ((unsigned)(myc[j] & (BUCKET_SZ - 1)) << 18);
            sbkt[p] = (unsigned short)b;
        }
    }
    __syncthreads();
    // linear writeout: consecutive threads -> consecutive addresses
    // within each bucket run (mean run 112B).
    for (int p = t; p < nloc; p += 1024) {
        int b = sbkt[p];
        pairs[ldiff[b] + p] = sbuf[p];
    }
}

// (2) per-bucket finalize: inline gbase reduction; counting sort by col
//     INTO LDS; coalesced writeout; emits offsets[], dis[].
__global__ void bucket_finalize(const unsigned int* __restrict__ pairs,
                                const int* __restrict__ gcur,
                                int* __restrict__ edata,
                                int* __restrict__ offsets,
                                float* __restrict__ dis,
                                int N, int E, int NB) {
    __shared__ int sbuf[CAP];         // 64KB col-sorted srcs
    __shared__ int ccnt[BUCKET_SZ];
    __shared__ int cexc[BUCKET_SZ];
    __shared__ int rnk[BUCKET_SZ];
    __shared__ int wsum[16];
    __shared__ int gb_s;
    int b = blockIdx.x, t = threadIdx.x;
    int pbase = b * CAP;
    int cnt = gcur[b * GSTRIDE] - pbase;

    // gbase = sum of counts of buckets before b (L2-hot reads)
    int part = 0;
    for (int j = t; j < b; j += 1024) part += gcur[j * GSTRIDE] - j * CAP;
#pragma unroll
    for (int off = 32; off; off >>= 1) part += __shfl_down(part, off, 64);
    if ((t & 63) == 0) wsum[t >> 6] = part;
    if (t < BUCKET_SZ) ccnt[t] = 0;
    __syncthreads();
    if (t == 0) {
        int g = 0;
#pragma unroll
        for (int w = 0; w < 16; ++w) g += wsum[w];
        gb_s = g;
    }
    // hist (concurrent with t==0's gbase finish; wsum untouched here)
    for (int i = t; i < cnt; i += 1024)
        atomicAdd(&ccnt[pairs[pbase + i] >> 18], 1);
    __syncthreads();

    // wave-scan ccnt[0..511] -> cexc (exclusive)
    int v = 0, incl = 0;
    if (t < 512) {
        v = ccnt[t];
        incl = v;
        int lane = t & 63;
#pragma unroll
        for (int off = 1; off < 64; off <<= 1) {
            int u = __shfl_up(incl, off, 64);
            if (lane >= off) incl += u;
        }
        if (lane == 63) wsum[t >> 6] = incl;
    }
    __syncthreads();
    if (t < 8) {
        int s = wsum[t];
        int inc2 = s;
#pragma unroll
        for (int off = 1; off < 8; off <<= 1) {
            int u = __shfl_up(inc2, off, 64);
            if (t >= off) inc2 += u;
        }
        wsum[t] = inc2 - s;
    }
    __syncthreads();
    if (t < 512) cexc[t] = (incl - v) + wsum[t >> 6];
    if (t < BUCKET_SZ) rnk[t] = 0;
    __syncthreads();

    int base = gb_s;
    int col0 = b << BUCKET_BITS;
    int ncols = min(BUCKET_SZ, N - col0);
    if (t < ncols) {
        int c = ccnt[t];
        offsets[col0 + t] = base + cexc[t];
        dis[col0 + t] = (c > 0) ? rsqrtf((float)c) : 0.0f;
    }
    __syncthreads();
    // pass 2: counting-sort into LDS (random-bank writes, ~2-4-way)
    for (int i = t; i < cnt; i += 1024) {
        unsigned p = pairs[pbase + i];  // L2-hot re-read
        int lc = p >> 18;
        int rk = atomicAdd(&rnk[lc], 1);
        sbuf[cexc[lc] + rk] = p & 0x3FFFF;
    }
    __syncthreads();
    // pass 3: perfectly coalesced writeout
    for (int i = t; i < cnt; i += 1024)
        edata[base + i] = sbuf[i];
}

// (3) flat streaming: y[row] = dis[row] * x[row] -> bf16. Perfect balance.
__global__ void yb_kernel(const float* __restrict__ x,
                          const float* __restrict__ dis,
                          unsigned short* __restrict__ yb, int N) {
    int tid = blockIdx.x * blockDim.x + threadIdx.x;
    int nth = gridDim.x * blockDim.x;
    int total = N * 16;
    for (int u = tid; u < total; u += nth) {
        int lr = u >> 4;
        int part = u & 15;
        float d = dis[lr];
        size_t o = (((size_t)lr) << 6) + part * 4;
        float4 vx = *(const float4*)(x + o);
        uint2 w;
        w.x = f2bf(vx.x * d) | (f2bf(vx.y * d) << 16);
        w.y = f2bf(vx.z * d) | (f2bf(vx.w * d) << 16);
        *(uint2*)(yb + o) = w;
    }
}

__device__ __forceinline__ void acc8(float* acc, uint4 q) {
    acc[0] += bf_lo(q.x);
    acc[1] += bf_hi(q.x);
    acc[2] += bf_lo(q.y);
    acc[3] += bf_hi(q.y);
    acc[4] += bf_lo(q.z);
    acc[5] += bf_hi(q.z);
    acc[6] += bf_lo(q.w);
    acc[7] += bf_hi(q.w);
}

// Wave = 8 subgroups x 8 lanes; each SUB owns ONE destination node
// (8 dests per wave). Lane holds 8 fp32 dims. Hot loop = 8 edges in
// flight per sub (64 gathers outstanding per wave), dual accumulators.
// !FINAL (embb = yb):  zb[c] = bf16( dis[c]^2 * acc )
//  FINAL (embb = zb):  out = (x + zb/dis + dis*acc)/3
template <bool FINAL>
__global__ void agg_kernel(const unsigned short* __restrict__ embb,
                           const int* __restrict__ edata,
                           const int* __restrict__ offsets,
                           const float* __restrict__ dis,
                           const float* __restrict__ x,        // FINAL only
                           unsigned short* __restrict__ outb,  // !FINAL
                           float* __restrict__ outf,           // FINAL
                           int n) {
    int wave = (blockIdx.x * blockDim.x + threadIdx.x) >> 6;
    int lane = threadIdx.x & 63;
    int sub = lane >> 3;
    int dest = (wave << 3) + sub;
    if (dest >= n) return;
    int dimo = (lane & 7) * 8;

    int s = offsets[dest];
    int e = offsets[dest + 1];

    float a0[8] = {0, 0, 0, 0, 0, 0, 0, 0};
    float a1[8] = {0, 0, 0, 0, 0, 0, 0, 0};
    const unsigned short* eb = embb + dimo;

    int k = s;
    int kfull = s + ((e - s) & ~7);
    for (; k < kfull; k += 8) {
        int s0 = edata[k];
        int s1 = edata[k + 1];
        int s2 = edata[k + 2];
        int s3 = edata[k + 3];
        int s4 = edata[k + 4];
        int s5 = edata[k + 5];
        int s6 = edata[k + 6];
        int s7 = edata[k + 7];
        uint4 q0 = *(const uint4*)(eb + ((size_t)s0 << 6));
        uint4 q1 = *(const uint4*)(eb + ((size_t)s1 << 6));
        uint4 q2 = *(const uint4*)(eb + ((size_t)s2 << 6));
        uint4 q3 = *(const uint4*)(eb + ((size_t)s3 << 6));
        uint4 q4 = *(const uint4*)(eb + ((size_t)s4 << 6));
        uint4 q5 = *(const uint4*)(eb + ((size_t)s5 << 6));
        uint4 q6 = *(const uint4*)(eb + ((size_t)s6 << 6));
        uint4 q7 = *(const uint4*)(eb + ((size_t)s7 << 6));
        acc8(a0, q0);
        acc8(a1, q1);
        acc8(a0, q2);
        acc8(a1, q3);
        acc8(a0, q4);
        acc8(a1, q5);
        acc8(a0, q6);
        acc8(a1, q7);
    }
    if (k < e) {  // tail < 8
        int s0 = edata[k];
        int s1 = (k + 1 < e) ? edata[k + 1] : -1;
        int s2 = (k + 2 < e) ? edata[k + 2] : -1;
        int s3 = (k + 3 < e) ? edata[k + 3] : -1;
        int s4 = (k + 4 < e) ? edata[k + 4] : -1;
        int s5 = (k + 5 < e) ? edata[k + 5] : -1;
        int s6 = (k + 6 < e) ? edata[k + 6] : -1;
        int s7 = (k + 7 < e) ? edata[k + 7] : -1;
        uint4 q0, q1, q2, q3, q4, q5, q6, q7;
        q0 = *(const uint4*)(eb + ((size_t)s0 << 6));
        if (s1 >= 0) q1 = *(const uint4*)(eb + ((size_t)s1 << 6));
        if (s2 >= 0) q2 = *(const uint4*)(eb + ((size_t)s2 << 6));
        if (s3 >= 0) q3 = *(const uint4*)(eb + ((size_t)s3 << 6));
        if (s4 >= 0) q4 = *(const uint4*)(eb + ((size_t)s4 << 6));
        if (s5 >= 0) q5 = *(const uint4*)(eb + ((size_t)s5 << 6));
        if (s6 >= 0) q6 = *(const uint4*)(eb + ((size_t)s6 << 6));
        if (s7 >= 0) q7 = *(const uint4*)(eb + ((size_t)s7 << 6));
        acc8(a0, q0);
        if (s1 >= 0) acc8(a1, q1);
        if (s2 >= 0) acc8(a0, q2);
        if (s3 >= 0) acc8(a1, q3);
        if (s4 >= 0) acc8(a0, q4);
        if (s5 >= 0) acc8(a1, q5);
        if (s6 >= 0) acc8(a0, q6);
        if (s7 >= 0) acc8(a1, q7);
    }

    float acc[8];
#pragma unroll
    for (int j = 0; j < 8; ++j) acc[j] = a0[j] + a1[j];

    float dc = dis[dest];
    size_t o = ((size_t)dest << 6) + dimo;
    if (FINAL) {
        float rd = (dc > 0.0f) ? 1.0f / dc : 0.0f;  // emb1 = z * rd
        f32x4 xa = __builtin_nontemporal_load((const f32x4*)(x + o));
        f32x4 xc = __builtin_nontemporal_load((const f32x4*)(x + o) + 1);
        uint4 qz = *(const uint4*)(embb + o);  // own z (bf16), L2-hot
        const float k3 = 1.0f / 3.0f;
        f32x4 r0, r1;
        r0.x = (xa.x + bf_lo(qz.x) * rd + dc * acc[0]) * k3;
        r0.y = (xa.y + bf_hi(qz.x) * rd + dc * acc[1]) * k3;
        r0.z = (xa.z + bf_lo(qz.y) * rd + dc * acc[2]) * k3;
        r0.w = (xa.w + bf_hi(qz.y) * rd + dc * acc[3]) * k3;
        r1.x = (xc.x + bf_lo(qz.z) * rd + dc * acc[4]) * k3;
        r1.y = (xc.y + bf_hi(qz.z) * rd + dc * acc[5]) * k3;
        r1.z = (xc.z + bf_lo(qz.w) * rd + dc * acc[6]) * k3;
        r1.w = (xc.w + bf_hi(qz.w) * rd + dc * acc[7]) * k3;
        __builtin_nontemporal_store(r0, (f32x4*)(outf + o));
        __builtin_nontemporal_store(r1, (f32x4*)(outf + o) + 1);
    } else {
        float zs = dc * dc;  // z = dis^2 * acc
        uint4 q;
        q.x = f2bf(zs * acc[0]) | (f2bf(zs * acc[1]) << 16);
        q.y = f2bf(zs * acc[2]) | (f2bf(zs * acc[3]) << 16);
        q.z = f2bf(zs * acc[4]) | (f2bf(zs * acc[5]) << 16);
        q.w = f2bf(zs * acc[6]) | (f2bf(zs * acc[7]) << 16);
        *(uint4*)(outb + o) = q;  // reused next layer: keep cached
    }
}

extern "C" void kernel_launch(void* const* d_in, const int* in_sizes, int n_in,
                              void* d_out, int out_size, void* d_ws, size_t ws_size,
                              hipStream_t stream) {
    const float* x  = (const float*)d_in[0];
    const int*   ei = (const int*)d_in[1];
    const int E = in_sizes[1] / 2;
    const int N = in_sizes[0] / EMB_DIM;  // 150000

    const int* rows = ei;       // edge_index[0]
    const int* cols = ei + E;   // edge_index[1]

    const int NB = (N + BUCKET_SZ - 1) >> BUCKET_BITS;  // 293
    const int NBLK = (E + EPB - 1) / EPB;               // 489

    // Workspace layout (ints):
    //   gcur[512*GSTRIDE]
    //   dis[150080] offsets[150080] edata[E]
    //   yb[N*64 bf16] = 4.8M ints
    //   region R: zb[N*64 bf16] overlapped by pairs[NB*CAP] (dead before agg1)
    int*   gcur    = (int*)d_ws;
    float* dis     = (float*)(gcur + 512 * GSTRIDE);
    int*   offsets = (int*)(dis + 150080);
    int*   edata   = offsets + 150080;
    unsigned short* yb = (unsigned short*)(edata + E);
    unsigned short* zb = yb + (size_t)N * EMB_DIM;
    unsigned int* pairs = (unsigned int*)zb;  // lifetime: fused_scatter..finalize
    float* out = (float*)d_out;

    init_kernel<<<1, 512, 0, stream>>>(gcur, offsets, NB, N, E);
    fused_scatter<<<NBLK, 1024, 0, stream>>>(rows, cols, gcur, pairs, E, NB);
    bucket_finalize<<<NB, 1024, 0, stream>>>(pairs, gcur, edata, offsets,
                                             dis, N, E, NB);
    yb_kernel<<<2048, 256, 0, stream>>>(x, dis, yb, N);

    int agg_waves = (N + 7) / 8;                 // 8 dests per wave
    int agg_blocks = (agg_waves + 3) / 4;        // 4 waves per 256-thread block
    // layer 1: yb -> zb (= dis^2 * sum y)
    agg_kernel<false><<<agg_blocks, 256, 0, stream>>>(yb, edata, offsets, dis,
                                                      nullptr, zb, nullptr, N);
    // layer 2 + final: out = (x + zb/dis + dis*sum zb[src]) / 3
    agg_kernel<true><<<agg_blocks, 256, 0, stream>>>(zb, edata, offsets, dis,
                                                     x, nullptr, out, N);
}